// Round 1
// baseline (4687.772 us; speedup 1.0000x reference)
//
#include <hip/hip_runtime.h>

#define HID 128

// ---------------- degree / norm prep ----------------

__global__ void deg_kernel(const int* __restrict__ dst, float* __restrict__ deg, int E) {
    int i = blockIdx.x * blockDim.x + threadIdx.x;
    if (i < E) atomicAdd(&deg[dst[i]], 1.0f);
}

__global__ void dinv_kernel(float* __restrict__ deg, int N) {
    int i = blockIdx.x * blockDim.x + threadIdx.x;
    if (i < N) deg[i] = rsqrtf(deg[i] + 1.0f);  // +1 = self loop
}

// ---------------- edge scatter-add ----------------
// 32 threads per edge, 4 floats per thread (128 features).
__global__ __launch_bounds__(256) void scatter_kernel(
    const float* __restrict__ hs, float* __restrict__ agg,
    const int* __restrict__ src, const int* __restrict__ dst, int E) {
    long long idx = (long long)blockIdx.x * blockDim.x + threadIdx.x;
    int e = (int)(idx >> 5);
    if (e >= E) return;
    int c = ((int)idx & 31) * 4;
    int s = src[e], d = dst[e];
    const float4 v = *(const float4*)(hs + (size_t)s * HID + c);
    float* p = agg + (size_t)d * HID + c;
    atomicAdd(p + 0, v.x);
    atomicAdd(p + 1, v.y);
    atomicAdd(p + 2, v.z);
    atomicAdd(p + 3, v.w);
}

// ---------------- finalize: out = relu((agg + hs_self) * dinv + b) ----------------
__global__ __launch_bounds__(256) void finalize_kernel(
    const float* __restrict__ agg, const float* __restrict__ hs,
    const float* __restrict__ dinv, const float* __restrict__ bias,
    float* __restrict__ out, int N) {
    long long idx = (long long)blockIdx.x * blockDim.x + threadIdx.x;
    int i = (int)(idx >> 5);
    if (i >= N) return;
    int c = ((int)idx & 31) * 4;
    float di = dinv[i];
    float4 a = *(const float4*)(agg + (size_t)i * HID + c);
    float4 h = *(const float4*)(hs + (size_t)i * HID + c);
    float4 b = *(const float4*)(bias + c);
    float4 r;
    r.x = fmaxf((a.x + h.x) * di + b.x, 0.0f);
    r.y = fmaxf((a.y + h.y) * di + b.y, 0.0f);
    r.z = fmaxf((a.z + h.z) * di + b.z, 0.0f);
    r.w = fmaxf((a.w + h.w) * di + b.w, 0.0f);
    *(float4*)(out + (size_t)i * HID + c) = r;
}

// ---------------- fp32 tiled GEMM: C[N x M] = epilogue(A[N x K] @ W[K x M]) ----------------
// BM=BN=64, BK=16, 256 threads, 4x4 micro-tile per thread.
// SCALE: multiply row by rowscale[row] (dinv).  BIAS: add bias[col].  RELU.
template <bool SCALE, bool BIAS, bool RELU>
__global__ __launch_bounds__(256) void gemm_kernel(
    const float* __restrict__ A, const float* __restrict__ W,
    const float* __restrict__ bias, const float* __restrict__ rowscale,
    float* __restrict__ C, int N, int K, int M) {
    const int BM = 64, BN = 64, BK = 16;
    __shared__ float As[BK][BM];  // transposed: As[k][m]
    __shared__ float Bs[BK][BN];

    int bm = blockIdx.y * BM;
    int bn = blockIdx.x * BN;
    int tid = threadIdx.x;
    int tx = tid & 15;   // 0..15 -> cols
    int ty = tid >> 4;   // 0..15 -> rows

    float acc[4][4] = {};

    for (int k0 = 0; k0 < K; k0 += BK) {
        // A tile: 64 rows x 16 k. Each thread loads one float4 along k.
        {
            int r = tid >> 2;          // 0..63
            int kq = (tid & 3) * 4;    // 0,4,8,12
            int row = bm + r;
            float4 v = make_float4(0.f, 0.f, 0.f, 0.f);
            if (row < N) v = *(const float4*)(A + (size_t)row * K + k0 + kq);
            As[kq + 0][r] = v.x;
            As[kq + 1][r] = v.y;
            As[kq + 2][r] = v.z;
            As[kq + 3][r] = v.w;
        }
        // B tile: 16 k x 64 n. Each thread loads one float4 along n.
        {
            int k = tid >> 4;          // 0..15
            int n4 = (tid & 15) * 4;   // 0..60
            float4 w = *(const float4*)(W + (size_t)(k0 + k) * M + bn + n4);
            *(float4*)&Bs[k][n4] = w;
        }
        __syncthreads();

#pragma unroll
        for (int k = 0; k < BK; ++k) {
            float a0 = As[k][ty * 4 + 0];
            float a1 = As[k][ty * 4 + 1];
            float a2 = As[k][ty * 4 + 2];
            float a3 = As[k][ty * 4 + 3];
            float b0 = Bs[k][tx * 4 + 0];
            float b1 = Bs[k][tx * 4 + 1];
            float b2 = Bs[k][tx * 4 + 2];
            float b3 = Bs[k][tx * 4 + 3];
            acc[0][0] += a0 * b0; acc[0][1] += a0 * b1; acc[0][2] += a0 * b2; acc[0][3] += a0 * b3;
            acc[1][0] += a1 * b0; acc[1][1] += a1 * b1; acc[1][2] += a1 * b2; acc[1][3] += a1 * b3;
            acc[2][0] += a2 * b0; acc[2][1] += a2 * b1; acc[2][2] += a2 * b2; acc[2][3] += a2 * b3;
            acc[3][0] += a3 * b0; acc[3][1] += a3 * b1; acc[3][2] += a3 * b2; acc[3][3] += a3 * b3;
        }
        __syncthreads();
    }

    // epilogue
#pragma unroll
    for (int i = 0; i < 4; ++i) {
        int row = bm + ty * 4 + i;
        if (row >= N) continue;
        float rs = 1.0f;
        if (SCALE) rs = rowscale[row];
        int col = bn + tx * 4;
        float4 v;
        v.x = acc[i][0]; v.y = acc[i][1]; v.z = acc[i][2]; v.w = acc[i][3];
        if (SCALE) { v.x *= rs; v.y *= rs; v.z *= rs; v.w *= rs; }
        if (BIAS) {
            float4 b = *(const float4*)(bias + col);
            v.x += b.x; v.y += b.y; v.z += b.z; v.w += b.w;
        }
        if (RELU) {
            v.x = fmaxf(v.x, 0.f); v.y = fmaxf(v.y, 0.f);
            v.z = fmaxf(v.z, 0.f); v.w = fmaxf(v.w, 0.f);
        }
        *(float4*)(C + (size_t)row * M + col) = v;
    }
}

// ---------------- host launch ----------------

extern "C" void kernel_launch(void* const* d_in, const int* in_sizes, int n_in,
                              void* d_out, int out_size, void* d_ws, size_t ws_size,
                              hipStream_t stream) {
    const float* x   = (const float*)d_in[0];
    const int*   ei  = (const int*)d_in[1];
    const float* Wg0 = (const float*)d_in[2];
    const float* bg0 = (const float*)d_in[3];
    const float* Wg1 = (const float*)d_in[4];
    const float* bg1 = (const float*)d_in[5];
    const float* Wg2 = (const float*)d_in[6];
    const float* bg2 = (const float*)d_in[7];
    const float* Wm0 = (const float*)d_in[8];
    const float* bm0 = (const float*)d_in[9];
    const float* Wm1 = (const float*)d_in[10];
    const float* bm1 = (const float*)d_in[11];
    float* out = (float*)d_out;

    const int N  = in_sizes[0] / HID;   // 50000
    const int E  = in_sizes[1] / 2;     // 800000
    const int M0 = in_sizes[9];         // 512
    const int M1 = in_sizes[11];        // 256

    const int* src = ei;
    const int* dst = ei + E;

    // workspace layout
    char* ws = (char*)d_ws;
    size_t offA = ((size_t)N * 4 + 255) & ~(size_t)255;
    size_t offB = offA + (size_t)N * HID * 4;
    size_t offC = offB + (size_t)N * HID * 4;
    size_t offM = offC + (size_t)N * HID * 4;
    float* dinv = (float*)ws;
    float* A    = (float*)(ws + offA);   // hs = (h @ W) * dinv[row]
    float* B    = (float*)(ws + offB);   // agg
    float* C    = (float*)(ws + offC);   // layer output
    float* Mbuf = (float*)(ws + offM);   // MLP hidden (N x 512)

    // degree + rsqrt norm
    hipMemsetAsync(dinv, 0, (size_t)N * 4, stream);
    deg_kernel<<<(E + 255) / 256, 256, 0, stream>>>(dst, dinv, E);
    dinv_kernel<<<(N + 255) / 256, 256, 0, stream>>>(dinv, N);

    const float* Wg[3] = {Wg0, Wg1, Wg2};
    const float* bg[3] = {bg0, bg1, bg2};
    const float* cur = x;
    long long scatterThreads = (long long)E * 32;
    long long finThreads = (long long)N * 32;
    for (int l = 0; l < 3; ++l) {
        dim3 g(HID / 64, (N + 63) / 64);
        gemm_kernel<true, false, false><<<g, 256, 0, stream>>>(
            cur, Wg[l], nullptr, dinv, A, N, HID, HID);
        hipMemsetAsync(B, 0, (size_t)N * HID * 4, stream);
        scatter_kernel<<<(int)((scatterThreads + 255) / 256), 256, 0, stream>>>(A, B, src, dst, E);
        finalize_kernel<<<(int)((finThreads + 255) / 256), 256, 0, stream>>>(B, A, dinv, bg[l], C, N);
        cur = C;
    }

    // MLP head
    gemm_kernel<false, true, true><<<dim3(M0 / 64, (N + 63) / 64), 256, 0, stream>>>(
        C, Wm0, bm0, nullptr, Mbuf, N, HID, M0);
    gemm_kernel<false, true, true><<<dim3(M1 / 64, (N + 63) / 64), 256, 0, stream>>>(
        Mbuf, Wm1, bm1, nullptr, out, N, M0, M1);
}

// Round 2
// 893.998 us; speedup vs baseline: 5.2436x; 5.2436x over previous
//
#include <hip/hip_runtime.h>

#define HID 128

// ---------------- CSR build ----------------

__global__ void deg_int_kernel(const int* __restrict__ dst, int* __restrict__ degi, int E) {
    int i = blockIdx.x * blockDim.x + threadIdx.x;
    if (i < E) atomicAdd(&degi[dst[i]], 1);
}

// single-block exclusive scan of degi[0..N) -> rowptr[0..N]
__global__ __launch_bounds__(1024) void scan_kernel(
    const int* __restrict__ degi, int* __restrict__ rowptr, int N) {
    __shared__ int smem[1024];
    __shared__ int carry_s;
    if (threadIdx.x == 0) carry_s = 0;
    __syncthreads();
    for (int base = 0; base < N; base += 1024) {
        int i = base + (int)threadIdx.x;
        int v = (i < N) ? degi[i] : 0;
        smem[threadIdx.x] = v;
        __syncthreads();
        for (int off = 1; off < 1024; off <<= 1) {
            int t = (threadIdx.x >= (unsigned)off) ? smem[threadIdx.x - off] : 0;
            __syncthreads();
            smem[threadIdx.x] += t;
            __syncthreads();
        }
        int incl = smem[threadIdx.x];
        int carry = carry_s;
        if (i < N) rowptr[i] = carry + incl - v;   // exclusive
        __syncthreads();
        if (threadIdx.x == 1023) carry_s = carry + incl;
        __syncthreads();
    }
    if (threadIdx.x == 0) rowptr[N] = carry_s;
}

__global__ void fill_kernel(const int* __restrict__ src, const int* __restrict__ dst,
                            int* __restrict__ cursor, int* __restrict__ col, int E) {
    int e = blockIdx.x * blockDim.x + threadIdx.x;
    if (e < E) {
        int d = dst[e];
        int pos = atomicAdd(&cursor[d], 1);
        col[pos] = src[e];
    }
}

__global__ void dinv_kernel(const int* __restrict__ degi, float* __restrict__ dinv, int N) {
    int i = blockIdx.x * blockDim.x + threadIdx.x;
    if (i < N) dinv[i] = rsqrtf((float)degi[i] + 1.0f);  // +1 = self loop
}

// ---------------- fused gather-reduce + finalize ----------------
// out[i] = relu((sum_{j in nbr(i)} hs[col[j]] + hs[i]) * dinv[i] + b)
// 32 threads per node, float4 (4 features) per thread.
__global__ __launch_bounds__(256) void gather_kernel(
    const float* __restrict__ hs, const int* __restrict__ rowptr,
    const int* __restrict__ col, const float* __restrict__ dinv,
    const float* __restrict__ bias, float* __restrict__ out, int N) {
    long long idx = (long long)blockIdx.x * blockDim.x + threadIdx.x;
    int i = (int)(idx >> 5);
    if (i >= N) return;
    int c = ((int)idx & 31) * 4;

    int beg = rowptr[i];
    int end = rowptr[i + 1];

    // self-loop term: hs[i] (hs already has dinv[row] folded in)
    float4 acc = *(const float4*)(hs + (size_t)i * HID + c);

    for (int j = beg; j < end; ++j) {
        int s = col[j];  // broadcast across the 32-lane group
        const float4 v = *(const float4*)(hs + (size_t)s * HID + c);
        acc.x += v.x; acc.y += v.y; acc.z += v.z; acc.w += v.w;
    }

    float di = dinv[i];
    float4 b = *(const float4*)(bias + c);
    float4 r;
    r.x = fmaxf(acc.x * di + b.x, 0.0f);
    r.y = fmaxf(acc.y * di + b.y, 0.0f);
    r.z = fmaxf(acc.z * di + b.z, 0.0f);
    r.w = fmaxf(acc.w * di + b.w, 0.0f);
    *(float4*)(out + (size_t)i * HID + c) = r;
}

// ---------------- fp32 tiled GEMM: C[N x M] = epilogue(A[N x K] @ W[K x M]) ----------------
// BM=BN=64, BK=16, 256 threads, 4x4 micro-tile per thread.
template <bool SCALE, bool BIAS, bool RELU>
__global__ __launch_bounds__(256) void gemm_kernel(
    const float* __restrict__ A, const float* __restrict__ W,
    const float* __restrict__ bias, const float* __restrict__ rowscale,
    float* __restrict__ C, int N, int K, int M) {
    const int BM = 64, BN = 64, BK = 16;
    __shared__ float As[BK][BM];  // transposed: As[k][m]
    __shared__ float Bs[BK][BN];

    int bm = blockIdx.y * BM;
    int bn = blockIdx.x * BN;
    int tid = threadIdx.x;
    int tx = tid & 15;   // cols
    int ty = tid >> 4;   // rows

    float acc[4][4] = {};

    for (int k0 = 0; k0 < K; k0 += BK) {
        {
            int r = tid >> 2;          // 0..63
            int kq = (tid & 3) * 4;    // 0,4,8,12
            int row = bm + r;
            float4 v = make_float4(0.f, 0.f, 0.f, 0.f);
            if (row < N) v = *(const float4*)(A + (size_t)row * K + k0 + kq);
            As[kq + 0][r] = v.x;
            As[kq + 1][r] = v.y;
            As[kq + 2][r] = v.z;
            As[kq + 3][r] = v.w;
        }
        {
            int k = tid >> 4;          // 0..15
            int n4 = (tid & 15) * 4;   // 0..60
            float4 w = *(const float4*)(W + (size_t)(k0 + k) * M + bn + n4);
            *(float4*)&Bs[k][n4] = w;
        }
        __syncthreads();

#pragma unroll
        for (int k = 0; k < BK; ++k) {
            float a0 = As[k][ty * 4 + 0];
            float a1 = As[k][ty * 4 + 1];
            float a2 = As[k][ty * 4 + 2];
            float a3 = As[k][ty * 4 + 3];
            float b0 = Bs[k][tx * 4 + 0];
            float b1 = Bs[k][tx * 4 + 1];
            float b2 = Bs[k][tx * 4 + 2];
            float b3 = Bs[k][tx * 4 + 3];
            acc[0][0] += a0 * b0; acc[0][1] += a0 * b1; acc[0][2] += a0 * b2; acc[0][3] += a0 * b3;
            acc[1][0] += a1 * b0; acc[1][1] += a1 * b1; acc[1][2] += a1 * b2; acc[1][3] += a1 * b3;
            acc[2][0] += a2 * b0; acc[2][1] += a2 * b1; acc[2][2] += a2 * b2; acc[2][3] += a2 * b3;
            acc[3][0] += a3 * b0; acc[3][1] += a3 * b1; acc[3][2] += a3 * b2; acc[3][3] += a3 * b3;
        }
        __syncthreads();
    }

#pragma unroll
    for (int i = 0; i < 4; ++i) {
        int row = bm + ty * 4 + i;
        if (row >= N) continue;
        float rs = 1.0f;
        if (SCALE) rs = rowscale[row];
        int col = bn + tx * 4;
        float4 v;
        v.x = acc[i][0]; v.y = acc[i][1]; v.z = acc[i][2]; v.w = acc[i][3];
        if (SCALE) { v.x *= rs; v.y *= rs; v.z *= rs; v.w *= rs; }
        if (BIAS) {
            float4 b = *(const float4*)(bias + col);
            v.x += b.x; v.y += b.y; v.z += b.z; v.w += b.w;
        }
        if (RELU) {
            v.x = fmaxf(v.x, 0.f); v.y = fmaxf(v.y, 0.f);
            v.z = fmaxf(v.z, 0.f); v.w = fmaxf(v.w, 0.f);
        }
        *(float4*)(C + (size_t)row * M + col) = v;
    }
}

// ---------------- host launch ----------------

extern "C" void kernel_launch(void* const* d_in, const int* in_sizes, int n_in,
                              void* d_out, int out_size, void* d_ws, size_t ws_size,
                              hipStream_t stream) {
    const float* x   = (const float*)d_in[0];
    const int*   ei  = (const int*)d_in[1];
    const float* Wg0 = (const float*)d_in[2];
    const float* bg0 = (const float*)d_in[3];
    const float* Wg1 = (const float*)d_in[4];
    const float* bg1 = (const float*)d_in[5];
    const float* Wg2 = (const float*)d_in[6];
    const float* bg2 = (const float*)d_in[7];
    const float* Wm0 = (const float*)d_in[8];
    const float* bm0 = (const float*)d_in[9];
    const float* Wm1 = (const float*)d_in[10];
    const float* bm1 = (const float*)d_in[11];
    float* out = (float*)d_out;

    const int N  = in_sizes[0] / HID;   // 50000
    const int E  = in_sizes[1] / 2;     // 800000
    const int M0 = in_sizes[9];         // 512
    const int M1 = in_sizes[11];        // 256

    const int* src = ei;
    const int* dst = ei + E;

    // workspace layout (256-byte aligned chunks)
    char* ws = (char*)d_ws;
    size_t off = 0;
    auto alloc = [&](size_t bytes) {
        void* p = ws + off;
        off += (bytes + 255) & ~(size_t)255;
        return p;
    };
    int*   degi   = (int*)alloc((size_t)N * 4);
    int*   rowptr = (int*)alloc((size_t)(N + 1) * 4);
    int*   cursor = (int*)alloc((size_t)N * 4);
    int*   col    = (int*)alloc((size_t)E * 4);
    float* dinv   = (float*)alloc((size_t)N * 4);
    float* A      = (float*)alloc((size_t)N * HID * 4);  // hs = (h @ W) * dinv[row]
    float* C      = (float*)alloc((size_t)N * HID * 4);  // layer output
    float* Mbuf   = (float*)alloc((size_t)N * 512 * 4);  // MLP hidden

    // ---- CSR build (once per call; reused by all 3 layers) ----
    hipMemsetAsync(degi, 0, (size_t)N * 4, stream);
    deg_int_kernel<<<(E + 255) / 256, 256, 0, stream>>>(dst, degi, E);
    scan_kernel<<<1, 1024, 0, stream>>>(degi, rowptr, N);
    hipMemcpyAsync(cursor, rowptr, (size_t)N * 4, hipMemcpyDeviceToDevice, stream);
    fill_kernel<<<(E + 255) / 256, 256, 0, stream>>>(src, dst, cursor, col, E);
    dinv_kernel<<<(N + 255) / 256, 256, 0, stream>>>(degi, dinv, N);

    const float* Wg[3] = {Wg0, Wg1, Wg2};
    const float* bg[3] = {bg0, bg1, bg2};
    const float* cur = x;
    long long gatherThreads = (long long)N * 32;
    for (int l = 0; l < 3; ++l) {
        dim3 g(HID / 64, (N + 63) / 64);
        gemm_kernel<true, false, false><<<g, 256, 0, stream>>>(
            cur, Wg[l], nullptr, dinv, A, N, HID, HID);
        gather_kernel<<<(int)((gatherThreads + 255) / 256), 256, 0, stream>>>(
            A, rowptr, col, dinv, bg[l], C, N);
        cur = C;
    }

    // MLP head
    gemm_kernel<false, true, true><<<dim3(M0 / 64, (N + 63) / 64), 256, 0, stream>>>(
        C, Wm0, bm0, nullptr, Mbuf, N, HID, M0);
    gemm_kernel<false, true, true><<<dim3(M1 / 64, (N + 63) / 64), 256, 0, stream>>>(
        Mbuf, Wm1, bm1, nullptr, out, N, M0, M1);
}

// Round 3
// 578.442 us; speedup vs baseline: 8.1041x; 1.5455x over previous
//
#include <hip/hip_runtime.h>

#define HID 128

using short8  = __attribute__((ext_vector_type(8))) short;
using float4v = __attribute__((ext_vector_type(4))) float;

// ---- fp32 -> bf16 (RNE) helpers ----
__device__ __forceinline__ unsigned short f2bf(float f) {
    unsigned u = __float_as_uint(f);
    u = u + 0x7fff + ((u >> 16) & 1);
    return (unsigned short)(u >> 16);
}
__device__ __forceinline__ float bf2f(unsigned short h) {
    return __uint_as_float(((unsigned)h) << 16);
}
__device__ __forceinline__ void split2(float x, unsigned short& hi, unsigned short& lo) {
    hi = f2bf(x);
    lo = f2bf(x - bf2f(hi));
}

// ---------------- CSR build ----------------

__global__ void deg_int_kernel(const int* __restrict__ dst, int* __restrict__ degi, int E) {
    int i = blockIdx.x * blockDim.x + threadIdx.x;
    if (i < E) atomicAdd(&degi[dst[i]], 1);
}

// phase 1: inclusive scan within 1024-chunks
__global__ __launch_bounds__(1024) void scan1_kernel(
    const int* __restrict__ in, int* __restrict__ incl, int* __restrict__ bsums, int N) {
    __shared__ int sm[1024];
    int i = blockIdx.x * 1024 + threadIdx.x;
    int v = (i < N) ? in[i] : 0;
    sm[threadIdx.x] = v;
    __syncthreads();
    for (int off = 1; off < 1024; off <<= 1) {
        int t = (threadIdx.x >= (unsigned)off) ? sm[threadIdx.x - off] : 0;
        __syncthreads();
        sm[threadIdx.x] += t;
        __syncthreads();
    }
    if (i < N) incl[i] = sm[threadIdx.x];
    if (threadIdx.x == 1023) bsums[blockIdx.x] = sm[1023];
}

// phase 2: exclusive scan of block sums (nblk <= 1024)
__global__ __launch_bounds__(1024) void scan2_kernel(int* __restrict__ bsums, int nblk) {
    __shared__ int sm[1024];
    int t = threadIdx.x;
    int v = (t < nblk) ? bsums[t] : 0;
    sm[t] = v;
    __syncthreads();
    for (int off = 1; off < 1024; off <<= 1) {
        int u = (t >= (unsigned)off) ? sm[t - off] : 0;
        __syncthreads();
        sm[t] += u;
        __syncthreads();
    }
    if (t < nblk) bsums[t] = sm[t] - v;  // exclusive
}

// phase 3: rowptr (exclusive) + cursor copy + dinv
__global__ void scan3_kernel(const int* __restrict__ incl, const int* __restrict__ degi,
                             const int* __restrict__ bsums, int* __restrict__ rowptr,
                             int* __restrict__ cursor, float* __restrict__ dinv, int N, int E) {
    int i = blockIdx.x * blockDim.x + threadIdx.x;
    if (i < N) {
        int r = bsums[i >> 10] + incl[i] - degi[i];
        rowptr[i] = r;
        cursor[i] = r;
        dinv[i] = rsqrtf((float)degi[i] + 1.0f);
    }
    if (i == 0) rowptr[N] = E;
}

__global__ void fill_kernel(const int* __restrict__ src, const int* __restrict__ dst,
                            int* __restrict__ cursor, int* __restrict__ col, int E) {
    int e = blockIdx.x * blockDim.x + threadIdx.x;
    if (e < E) {
        int d = dst[e];
        int pos = atomicAdd(&cursor[d], 1);
        col[pos] = src[e];
    }
}

// ---------------- input / weight conversion ----------------

// x (fp32 [N][HID]) -> split planes
__global__ void xsplit_kernel(const float* __restrict__ x, unsigned short* __restrict__ Xhi,
                              unsigned short* __restrict__ Xlo, int total4) {
    int i = blockIdx.x * blockDim.x + threadIdx.x;
    if (i >= total4) return;
    const float4 v = *(const float4*)(x + (size_t)i * 4);
    ushort4 h, l;
    split2(v.x, h.x, l.x);
    split2(v.y, h.y, l.y);
    split2(v.z, h.z, l.z);
    split2(v.w, h.w, l.w);
    *(ushort4*)(Xhi + (size_t)i * 4) = h;
    *(ushort4*)(Xlo + (size_t)i * 4) = l;
}

// W (fp32 [K][M]) -> transposed split planes [M][K]
__global__ void wsplit_kernel(const float* __restrict__ W, unsigned short* __restrict__ Whi,
                              unsigned short* __restrict__ Wlo, int K, int M) {
    int idx = blockIdx.x * blockDim.x + threadIdx.x;
    if (idx >= K * M) return;
    int k = idx / M;
    int m = idx - k * M;
    unsigned short hi, lo;
    split2(W[idx], hi, lo);
    Whi[(size_t)m * K + k] = hi;
    Wlo[(size_t)m * K + k] = lo;
}

// ---------------- fused gather-reduce + finalize -> split planes ----------------
__global__ __launch_bounds__(256) void gather_kernel(
    const float* __restrict__ hs, const int* __restrict__ rowptr,
    const int* __restrict__ col, const float* __restrict__ dinv,
    const float* __restrict__ bias, unsigned short* __restrict__ Chi,
    unsigned short* __restrict__ Clo, int N) {
    long long idx = (long long)blockIdx.x * blockDim.x + threadIdx.x;
    int i = (int)(idx >> 5);
    if (i >= N) return;
    int c = ((int)idx & 31) * 4;

    int beg = rowptr[i];
    int end = rowptr[i + 1];

    float4 acc = *(const float4*)(hs + (size_t)i * HID + c);  // self-loop

    for (int j = beg; j < end; ++j) {
        int s = col[j];
        const float4 v = *(const float4*)(hs + (size_t)s * HID + c);
        acc.x += v.x; acc.y += v.y; acc.z += v.z; acc.w += v.w;
    }

    float di = dinv[i];
    float4 b = *(const float4*)(bias + c);
    float rx = fmaxf(acc.x * di + b.x, 0.0f);
    float ry = fmaxf(acc.y * di + b.y, 0.0f);
    float rz = fmaxf(acc.z * di + b.z, 0.0f);
    float rw = fmaxf(acc.w * di + b.w, 0.0f);
    ushort4 h, l;
    split2(rx, h.x, l.x);
    split2(ry, h.y, l.y);
    split2(rz, h.z, l.z);
    split2(rw, h.w, l.w);
    *(ushort4*)(Chi + (size_t)i * HID + c) = h;
    *(ushort4*)(Clo + (size_t)i * HID + c) = l;
}

// ---------------- split-bf16 MFMA GEMM ----------------
// C[N x M] = epilogue(A[N x K] @ W[K x M]), A given as bf16 hi/lo planes [Npad][K],
// W given as transposed bf16 hi/lo planes [M][K].
// 128x128 tile, 4 waves (2x2), each wave 64x64 via 4x4 of 16x16x32 MFMA tiles.
// Product a*b ~= ah*bh + ah*bl + al*bh  (3 MFMA per tile per 32-k chunk).
template <bool SCALE, bool BIAS, bool RELU, bool SPLIT>
__global__ __launch_bounds__(256, 2) void gemm_mfma(
    const unsigned short* __restrict__ Ahi, const unsigned short* __restrict__ Alo,
    const unsigned short* __restrict__ Bhi, const unsigned short* __restrict__ Blo,
    const float* __restrict__ bias, const float* __restrict__ rowscale,
    float* __restrict__ outF, unsigned short* __restrict__ outHi,
    unsigned short* __restrict__ outLo, int Nout, int K, int M) {
    __shared__ unsigned short lds[4 * 128 * 32];  // Ah, Al, Bh, Bl: [128 rows][32 k]
    unsigned short* Ah = lds;
    unsigned short* Al = lds + 4096;
    unsigned short* Bh = lds + 8192;
    unsigned short* Bl = lds + 12288;

    const int tid = threadIdx.x;
    const int bm = blockIdx.y * 128;
    const int bn = blockIdx.x * 128;
    const int wave = tid >> 6, lane = tid & 63;
    const int quad = lane >> 4, c16 = lane & 15;
    const int wm = (wave >> 1) * 64, wn = (wave & 1) * 64;

    float4v acc[4][4];
#pragma unroll
    for (int a = 0; a < 4; ++a)
#pragma unroll
        for (int b = 0; b < 4; ++b)
#pragma unroll
            for (int r = 0; r < 4; ++r) acc[a][b][r] = 0.0f;

    const int r0 = tid >> 2;            // 0..63
    const int kc0 = (tid & 3) * 8;      // 0,8,16,24

    for (int k0 = 0; k0 < K; k0 += 32) {
        // global loads: 4 planes x 2 rows each (16B)
        const size_t aoff0 = (size_t)(bm + r0) * K + k0 + kc0;
        const size_t aoff1 = (size_t)(bm + r0 + 64) * K + k0 + kc0;
        const size_t boff0 = (size_t)(bn + r0) * K + k0 + kc0;
        const size_t boff1 = (size_t)(bn + r0 + 64) * K + k0 + kc0;
        uint4 vah0 = *(const uint4*)(Ahi + aoff0);
        uint4 vah1 = *(const uint4*)(Ahi + aoff1);
        uint4 val0 = *(const uint4*)(Alo + aoff0);
        uint4 val1 = *(const uint4*)(Alo + aoff1);
        uint4 vbh0 = *(const uint4*)(Bhi + boff0);
        uint4 vbh1 = *(const uint4*)(Bhi + boff1);
        uint4 vbl0 = *(const uint4*)(Blo + boff0);
        uint4 vbl1 = *(const uint4*)(Blo + boff1);

        __syncthreads();  // previous chunk's fragment reads done
        *(uint4*)&Ah[(size_t)tid * 8] = vah0;
        *(uint4*)&Ah[(size_t)(tid + 256) * 8] = vah1;
        *(uint4*)&Al[(size_t)tid * 8] = val0;
        *(uint4*)&Al[(size_t)(tid + 256) * 8] = val1;
        *(uint4*)&Bh[(size_t)tid * 8] = vbh0;
        *(uint4*)&Bh[(size_t)(tid + 256) * 8] = vbh1;
        *(uint4*)&Bl[(size_t)tid * 8] = vbl0;
        *(uint4*)&Bl[(size_t)(tid + 256) * 8] = vbl1;
        __syncthreads();

        short8 afh[4], afl[4], bfh[4], bfl[4];
#pragma unroll
        for (int t = 0; t < 4; ++t) {
            int am = wm + t * 16 + c16;
            afh[t] = *(const short8*)&Ah[am * 32 + quad * 8];
            afl[t] = *(const short8*)&Al[am * 32 + quad * 8];
            int bn_ = wn + t * 16 + c16;
            bfh[t] = *(const short8*)&Bh[bn_ * 32 + quad * 8];
            bfl[t] = *(const short8*)&Bl[bn_ * 32 + quad * 8];
        }
#pragma unroll
        for (int tm = 0; tm < 4; ++tm)
#pragma unroll
            for (int tn = 0; tn < 4; ++tn) {
                acc[tm][tn] = __builtin_amdgcn_mfma_f32_16x16x32_bf16(afh[tm], bfh[tn], acc[tm][tn], 0, 0, 0);
                acc[tm][tn] = __builtin_amdgcn_mfma_f32_16x16x32_bf16(afh[tm], bfl[tn], acc[tm][tn], 0, 0, 0);
                acc[tm][tn] = __builtin_amdgcn_mfma_f32_16x16x32_bf16(afl[tm], bfh[tn], acc[tm][tn], 0, 0, 0);
            }
    }

    // epilogue: C/D layout col=lane&15, row=quad*4+reg
#pragma unroll
    for (int tm = 0; tm < 4; ++tm) {
#pragma unroll
        for (int tn = 0; tn < 4; ++tn) {
            int colg = bn + wn + tn * 16 + c16;
            float bv = BIAS ? bias[colg] : 0.0f;
#pragma unroll
            for (int r = 0; r < 4; ++r) {
                int row = bm + wm + tm * 16 + quad * 4 + r;
                if (row >= Nout) continue;
                float v = acc[tm][tn][r];
                if (SCALE) v *= rowscale[row];
                if (BIAS) v += bv;
                if (RELU) v = fmaxf(v, 0.0f);
                if (SPLIT) {
                    unsigned short hi, lo;
                    split2(v, hi, lo);
                    outHi[(size_t)row * M + colg] = hi;
                    outLo[(size_t)row * M + colg] = lo;
                } else {
                    outF[(size_t)row * M + colg] = v;
                }
            }
        }
    }
}

// ---------------- host launch ----------------

extern "C" void kernel_launch(void* const* d_in, const int* in_sizes, int n_in,
                              void* d_out, int out_size, void* d_ws, size_t ws_size,
                              hipStream_t stream) {
    const float* x   = (const float*)d_in[0];
    const int*   ei  = (const int*)d_in[1];
    const float* Wg0 = (const float*)d_in[2];
    const float* bg0 = (const float*)d_in[3];
    const float* Wg1 = (const float*)d_in[4];
    const float* bg1 = (const float*)d_in[5];
    const float* Wg2 = (const float*)d_in[6];
    const float* bg2 = (const float*)d_in[7];
    const float* Wm0 = (const float*)d_in[8];
    const float* bm0 = (const float*)d_in[9];
    const float* Wm1 = (const float*)d_in[10];
    const float* bm1 = (const float*)d_in[11];
    float* out = (float*)d_out;

    const int N  = in_sizes[0] / HID;   // 50000
    const int E  = in_sizes[1] / 2;     // 800000
    const int M0 = in_sizes[9];         // 512
    const int M1 = in_sizes[11];        // 256
    const int Npad = ((N + 127) / 128) * 128;   // 50048
    const int nblk1024 = (N + 1023) / 1024;

    const int* src = ei;
    const int* dst = ei + E;

    char* ws = (char*)d_ws;
    size_t off = 0;
    auto alloc = [&](size_t bytes) {
        void* p = ws + off;
        off += (bytes + 255) & ~(size_t)255;
        return p;
    };
    // small buffers
    int* degi   = (int*)alloc((size_t)N * 4);
    int* tmp    = (int*)alloc((size_t)N * 4);
    int* bsums  = (int*)alloc(4096);
    int* rowptr = (int*)alloc((size_t)(N + 1) * 4);
    int* cursor = (int*)alloc((size_t)N * 4);
    int* colbuf = (int*)alloc((size_t)E * 4);
    float* dinv = (float*)alloc((size_t)N * 4);
    // weight planes (transposed, split)
    unsigned short* WgT_hi[3];
    unsigned short* WgT_lo[3];
    for (int l = 0; l < 3; ++l) {
        WgT_hi[l] = (unsigned short*)alloc((size_t)HID * HID * 2);
        WgT_lo[l] = (unsigned short*)alloc((size_t)HID * HID * 2);
    }
    unsigned short* Wm0T_hi = (unsigned short*)alloc((size_t)M0 * HID * 2);
    unsigned short* Wm0T_lo = (unsigned short*)alloc((size_t)M0 * HID * 2);
    unsigned short* Wm1T_hi = (unsigned short*)alloc((size_t)M1 * M0 * 2);
    unsigned short* Wm1T_lo = (unsigned short*)alloc((size_t)M1 * M0 * 2);
    // activation planes
    unsigned short* Chi = (unsigned short*)alloc((size_t)Npad * HID * 2);
    unsigned short* Clo = (unsigned short*)alloc((size_t)Npad * HID * 2);
    // overlay region: [Xhi | Xlo | A(fp32)] reused as [Mhi | Mlo]
    char* R = (char*)alloc((size_t)Npad * M0 * 2 * 2);  // 102.4 MB
    unsigned short* Xhi = (unsigned short*)R;
    unsigned short* Xlo = (unsigned short*)(R + (size_t)Npad * HID * 2);
    float* A = (float*)(R + (size_t)Npad * HID * 4);           // hs fp32 [N][HID]
    unsigned short* Mhi = (unsigned short*)R;
    unsigned short* Mlo = (unsigned short*)(R + (size_t)Npad * M0 * 2);

    // ---- CSR build ----
    hipMemsetAsync(degi, 0, (size_t)N * 4, stream);
    deg_int_kernel<<<(E + 255) / 256, 256, 0, stream>>>(dst, degi, E);
    scan1_kernel<<<nblk1024, 1024, 0, stream>>>(degi, tmp, bsums, N);
    scan2_kernel<<<1, 1024, 0, stream>>>(bsums, nblk1024);
    scan3_kernel<<<(N + 255) / 256, 256, 0, stream>>>(tmp, degi, bsums, rowptr, cursor, dinv, N, E);
    fill_kernel<<<(E + 255) / 256, 256, 0, stream>>>(src, dst, cursor, colbuf, E);

    // ---- conversions ----
    xsplit_kernel<<<(N * HID / 4 + 255) / 256, 256, 0, stream>>>(x, Xhi, Xlo, N * HID / 4);
    const float* WgArr[3] = {Wg0, Wg1, Wg2};
    for (int l = 0; l < 3; ++l)
        wsplit_kernel<<<(HID * HID + 255) / 256, 256, 0, stream>>>(WgArr[l], WgT_hi[l], WgT_lo[l], HID, HID);
    wsplit_kernel<<<(HID * M0 + 255) / 256, 256, 0, stream>>>(Wm0, Wm0T_hi, Wm0T_lo, HID, M0);
    wsplit_kernel<<<(M0 * M1 + 255) / 256, 256, 0, stream>>>(Wm1, Wm1T_hi, Wm1T_lo, M0, M1);

    // ---- 3 GCN layers ----
    const float* bg[3] = {bg0, bg1, bg2};
    const unsigned short* curHi = Xhi;
    const unsigned short* curLo = Xlo;
    long long gatherThreads = (long long)N * 32;
    for (int l = 0; l < 3; ++l) {
        gemm_mfma<true, false, false, false><<<dim3(1, Npad / 128), 256, 0, stream>>>(
            curHi, curLo, WgT_hi[l], WgT_lo[l], nullptr, dinv, A, nullptr, nullptr, N, HID, HID);
        gather_kernel<<<(int)((gatherThreads + 255) / 256), 256, 0, stream>>>(
            A, rowptr, colbuf, dinv, bg[l], Chi, Clo, N);
        curHi = Chi;
        curLo = Clo;
    }

    // ---- MLP head ----
    gemm_mfma<false, true, true, true><<<dim3(M0 / 128, Npad / 128), 256, 0, stream>>>(
        Chi, Clo, Wm0T_hi, Wm0T_lo, bm0, nullptr, nullptr, Mhi, Mlo, N, HID, M0);
    gemm_mfma<false, true, true, false><<<dim3(M1 / 128, Npad / 128), 256, 0, stream>>>(
        Mhi, Mlo, Wm1T_hi, Wm1T_lo, bm1, nullptr, out, nullptr, nullptr, N, M0, M1);
}

// Round 4
// 557.034 us; speedup vs baseline: 8.4156x; 1.0384x over previous
//
#include <hip/hip_runtime.h>

#define HID 128

using short8  = __attribute__((ext_vector_type(8))) short;
using float4v = __attribute__((ext_vector_type(4))) float;

// ---- fp32 -> bf16 (RNE) helpers ----
__device__ __forceinline__ unsigned short f2bf(float f) {
    unsigned u = __float_as_uint(f);
    u = u + 0x7fff + ((u >> 16) & 1);
    return (unsigned short)(u >> 16);
}
__device__ __forceinline__ float bf2f(unsigned short h) {
    return __uint_as_float(((unsigned)h) << 16);
}
__device__ __forceinline__ void split2(float x, unsigned short& hi, unsigned short& lo) {
    hi = f2bf(x);
    lo = f2bf(x - bf2f(hi));
}

// ---- async global->LDS, 16 B per lane (wave-uniform base + lane*16) ----
typedef const __attribute__((address_space(1))) unsigned int* gas_ptr;
typedef __attribute__((address_space(3))) unsigned int* las_ptr;
__device__ __forceinline__ void gld16(const unsigned short* g, unsigned short* l) {
    __builtin_amdgcn_global_load_lds((gas_ptr)g, (las_ptr)l, 16, 0, 0);
}

// ---------------- CSR build ----------------

__global__ void deg_int_kernel(const int* __restrict__ dst, int* __restrict__ degi, int E) {
    int i = blockIdx.x * blockDim.x + threadIdx.x;
    if (i < E) atomicAdd(&degi[dst[i]], 1);
}

__global__ __launch_bounds__(1024) void scan1_kernel(
    const int* __restrict__ in, int* __restrict__ incl, int* __restrict__ bsums, int N) {
    __shared__ int sm[1024];
    int i = blockIdx.x * 1024 + threadIdx.x;
    int v = (i < N) ? in[i] : 0;
    sm[threadIdx.x] = v;
    __syncthreads();
    for (int off = 1; off < 1024; off <<= 1) {
        int t = (threadIdx.x >= (unsigned)off) ? sm[threadIdx.x - off] : 0;
        __syncthreads();
        sm[threadIdx.x] += t;
        __syncthreads();
    }
    if (i < N) incl[i] = sm[threadIdx.x];
    if (threadIdx.x == 1023) bsums[blockIdx.x] = sm[1023];
}

__global__ __launch_bounds__(1024) void scan2_kernel(int* __restrict__ bsums, int nblk) {
    __shared__ int sm[1024];
    int t = threadIdx.x;
    int v = (t < nblk) ? bsums[t] : 0;
    sm[t] = v;
    __syncthreads();
    for (int off = 1; off < 1024; off <<= 1) {
        int u = (t >= (unsigned)off) ? sm[t - off] : 0;
        __syncthreads();
        sm[t] += u;
        __syncthreads();
    }
    if (t < nblk) bsums[t] = sm[t] - v;  // exclusive
}

__global__ void scan3_kernel(const int* __restrict__ incl, const int* __restrict__ degi,
                             const int* __restrict__ bsums, int* __restrict__ rowptr,
                             int* __restrict__ cursor, float* __restrict__ dinv, int N, int E) {
    int i = blockIdx.x * blockDim.x + threadIdx.x;
    if (i < N) {
        int r = bsums[i >> 10] + incl[i] - degi[i];
        rowptr[i] = r;
        cursor[i] = r;
        dinv[i] = rsqrtf((float)degi[i] + 1.0f);
    }
    if (i == 0) rowptr[N] = E;
}

__global__ void fill_kernel(const int* __restrict__ src, const int* __restrict__ dst,
                            int* __restrict__ cursor, int* __restrict__ col, int E) {
    int e = blockIdx.x * blockDim.x + threadIdx.x;
    if (e < E) {
        int d = dst[e];
        int pos = atomicAdd(&cursor[d], 1);
        col[pos] = src[e];
    }
}

// ---------------- input / weight conversion ----------------

__global__ void xsplit_kernel(const float* __restrict__ x, unsigned short* __restrict__ Xhi,
                              unsigned short* __restrict__ Xlo, int total4) {
    int i = blockIdx.x * blockDim.x + threadIdx.x;
    if (i >= total4) return;
    const float4 v = *(const float4*)(x + (size_t)i * 4);
    ushort4 h, l;
    split2(v.x, h.x, l.x);
    split2(v.y, h.y, l.y);
    split2(v.z, h.z, l.z);
    split2(v.w, h.w, l.w);
    *(ushort4*)(Xhi + (size_t)i * 4) = h;
    *(ushort4*)(Xlo + (size_t)i * 4) = l;
}

__global__ void wsplit_kernel(const float* __restrict__ W, unsigned short* __restrict__ Whi,
                              unsigned short* __restrict__ Wlo, int K, int M) {
    int idx = blockIdx.x * blockDim.x + threadIdx.x;
    if (idx >= K * M) return;
    int k = idx / M;
    int m = idx - k * M;
    unsigned short hi, lo;
    split2(W[idx], hi, lo);
    Whi[(size_t)m * K + k] = hi;
    Wlo[(size_t)m * K + k] = lo;
}

// ---------------- fused gather-reduce + finalize -> split planes ----------------
__global__ __launch_bounds__(256) void gather_kernel(
    const float* __restrict__ hs, const int* __restrict__ rowptr,
    const int* __restrict__ col, const float* __restrict__ dinv,
    const float* __restrict__ bias, unsigned short* __restrict__ Chi,
    unsigned short* __restrict__ Clo, int N) {
    long long idx = (long long)blockIdx.x * blockDim.x + threadIdx.x;
    int i = (int)(idx >> 5);
    if (i >= N) return;
    int c = ((int)idx & 31) * 4;

    int beg = rowptr[i];
    int end = rowptr[i + 1];

    float4 acc = *(const float4*)(hs + (size_t)i * HID + c);  // self-loop

    int j = beg;
    for (; j + 2 <= end; j += 2) {
        int s0 = col[j];
        int s1 = col[j + 1];
        const float4 v0 = *(const float4*)(hs + (size_t)s0 * HID + c);
        const float4 v1 = *(const float4*)(hs + (size_t)s1 * HID + c);
        acc.x += v0.x + v1.x;
        acc.y += v0.y + v1.y;
        acc.z += v0.z + v1.z;
        acc.w += v0.w + v1.w;
    }
    if (j < end) {
        int s = col[j];
        const float4 v = *(const float4*)(hs + (size_t)s * HID + c);
        acc.x += v.x; acc.y += v.y; acc.z += v.z; acc.w += v.w;
    }

    float di = dinv[i];
    float4 b = *(const float4*)(bias + c);
    float rx = fmaxf(acc.x * di + b.x, 0.0f);
    float ry = fmaxf(acc.y * di + b.y, 0.0f);
    float rz = fmaxf(acc.z * di + b.z, 0.0f);
    float rw = fmaxf(acc.w * di + b.w, 0.0f);
    ushort4 h, l;
    split2(rx, h.x, l.x);
    split2(ry, h.y, l.y);
    split2(rz, h.z, l.z);
    split2(rw, h.w, l.w);
    *(ushort4*)(Chi + (size_t)i * HID + c) = h;
    *(ushort4*)(Clo + (size_t)i * HID + c) = l;
}

// ---------------- split-bf16 MFMA GEMM with async LDS staging ----------------
// C[N x M] = epilogue(A[N x K] @ W[K x M]); A = bf16 hi/lo planes [Npad][K],
// W = transposed bf16 hi/lo planes [M][K].
// 128x128 tile, 4 waves (2x2), each wave 64x64 = 4x4 of 16x16x32 MFMA tiles.
// a*b ~= ah*bh + ah*bl + al*bh  (3 MFMA / tile / 32-k chunk).
template <bool SCALE, bool BIAS, bool RELU, bool SPLIT>
__global__ __launch_bounds__(256, 3) void gemm_mfma(
    const unsigned short* __restrict__ Ahi, const unsigned short* __restrict__ Alo,
    const unsigned short* __restrict__ Bhi, const unsigned short* __restrict__ Blo,
    const float* __restrict__ bias, const float* __restrict__ rowscale,
    float* __restrict__ outF, unsigned short* __restrict__ outHi,
    unsigned short* __restrict__ outLo, int Nout, int K, int M) {
    __shared__ unsigned short lds[4 * 128 * 32];  // Ah, Al, Bh, Bl: [128 rows][32 k]
    unsigned short* Ah = lds;
    unsigned short* Al = lds + 4096;
    unsigned short* Bh = lds + 8192;
    unsigned short* Bl = lds + 12288;

    const int tid = threadIdx.x;
    const int bm = blockIdx.y * 128;
    const int bn = blockIdx.x * 128;
    const int wave = tid >> 6, lane = tid & 63;
    const int quad = lane >> 4, c16 = lane & 15;
    const int wm = (wave >> 1) * 64, wn = (wave & 1) * 64;

    float4v acc[4][4];
#pragma unroll
    for (int a = 0; a < 4; ++a)
#pragma unroll
        for (int b = 0; b < 4; ++b)
#pragma unroll
            for (int r = 0; r < 4; ++r) acc[a][b][r] = 0.0f;

    const int r0 = tid >> 2;            // 0..63
    const int kc0 = (tid & 3) * 8;      // 0,8,16,24

    // per-thread global base pointers (advance by 32 k per chunk)
    const unsigned short* gAh0 = Ahi + (size_t)(bm + r0) * K + kc0;
    const unsigned short* gAh1 = Ahi + (size_t)(bm + r0 + 64) * K + kc0;
    const unsigned short* gAl0 = Alo + (size_t)(bm + r0) * K + kc0;
    const unsigned short* gAl1 = Alo + (size_t)(bm + r0 + 64) * K + kc0;
    const unsigned short* gBh0 = Bhi + (size_t)(bn + r0) * K + kc0;
    const unsigned short* gBh1 = Bhi + (size_t)(bn + r0 + 64) * K + kc0;
    const unsigned short* gBl0 = Blo + (size_t)(bn + r0) * K + kc0;
    const unsigned short* gBl1 = Blo + (size_t)(bn + r0 + 64) * K + kc0;

    // per-thread LDS slots (tid*16 B == wave-uniform base + lane*16 B)
    unsigned short* lAh0 = Ah + (size_t)tid * 8;
    unsigned short* lAh1 = Ah + (size_t)(tid + 256) * 8;
    unsigned short* lAl0 = Al + (size_t)tid * 8;
    unsigned short* lAl1 = Al + (size_t)(tid + 256) * 8;
    unsigned short* lBh0 = Bh + (size_t)tid * 8;
    unsigned short* lBh1 = Bh + (size_t)(tid + 256) * 8;
    unsigned short* lBl0 = Bl + (size_t)tid * 8;
    unsigned short* lBl1 = Bl + (size_t)(tid + 256) * 8;

    for (int k0 = 0; k0 < K; k0 += 32) {
        if (k0 != 0) __syncthreads();  // all waves done reading previous chunk
        gld16(gAh0 + k0, lAh0);
        gld16(gAh1 + k0, lAh1);
        gld16(gAl0 + k0, lAl0);
        gld16(gAl1 + k0, lAl1);
        gld16(gBh0 + k0, lBh0);
        gld16(gBh1 + k0, lBh1);
        gld16(gBl0 + k0, lBl0);
        gld16(gBl1 + k0, lBl1);
        __syncthreads();               // drains vmcnt (DMA done) + barrier

        short8 afh[4], afl[4], bfh[4], bfl[4];
#pragma unroll
        for (int t = 0; t < 4; ++t) {
            int am = wm + t * 16 + c16;
            afh[t] = *(const short8*)&Ah[am * 32 + quad * 8];
            afl[t] = *(const short8*)&Al[am * 32 + quad * 8];
            int bn_ = wn + t * 16 + c16;
            bfh[t] = *(const short8*)&Bh[bn_ * 32 + quad * 8];
            bfl[t] = *(const short8*)&Bl[bn_ * 32 + quad * 8];
        }
#pragma unroll
        for (int tm = 0; tm < 4; ++tm)
#pragma unroll
            for (int tn = 0; tn < 4; ++tn) {
                acc[tm][tn] = __builtin_amdgcn_mfma_f32_16x16x32_bf16(afh[tm], bfh[tn], acc[tm][tn], 0, 0, 0);
                acc[tm][tn] = __builtin_amdgcn_mfma_f32_16x16x32_bf16(afh[tm], bfl[tn], acc[tm][tn], 0, 0, 0);
                acc[tm][tn] = __builtin_amdgcn_mfma_f32_16x16x32_bf16(afl[tm], bfh[tn], acc[tm][tn], 0, 0, 0);
            }
    }

    // epilogue: C/D layout col=lane&15, row=quad*4+reg
#pragma unroll
    for (int tm = 0; tm < 4; ++tm) {
#pragma unroll
        for (int tn = 0; tn < 4; ++tn) {
            int colg = bn + wn + tn * 16 + c16;
            float bv = BIAS ? bias[colg] : 0.0f;
#pragma unroll
            for (int r = 0; r < 4; ++r) {
                int row = bm + wm + tm * 16 + quad * 4 + r;
                if (row >= Nout) continue;
                float v = acc[tm][tn][r];
                if (SCALE) v *= rowscale[row];
                if (BIAS) v += bv;
                if (RELU) v = fmaxf(v, 0.0f);
                if (SPLIT) {
                    unsigned short hi, lo;
                    split2(v, hi, lo);
                    outHi[(size_t)row * M + colg] = hi;
                    outLo[(size_t)row * M + colg] = lo;
                } else {
                    outF[(size_t)row * M + colg] = v;
                }
            }
        }
    }
}

// ---------------- host launch ----------------

extern "C" void kernel_launch(void* const* d_in, const int* in_sizes, int n_in,
                              void* d_out, int out_size, void* d_ws, size_t ws_size,
                              hipStream_t stream) {
    const float* x   = (const float*)d_in[0];
    const int*   ei  = (const int*)d_in[1];
    const float* Wg0 = (const float*)d_in[2];
    const float* bg0 = (const float*)d_in[3];
    const float* Wg1 = (const float*)d_in[4];
    const float* bg1 = (const float*)d_in[5];
    const float* Wg2 = (const float*)d_in[6];
    const float* bg2 = (const float*)d_in[7];
    const float* Wm0 = (const float*)d_in[8];
    const float* bm0 = (const float*)d_in[9];
    const float* Wm1 = (const float*)d_in[10];
    const float* bm1 = (const float*)d_in[11];
    float* out = (float*)d_out;

    const int N  = in_sizes[0] / HID;   // 50000
    const int E  = in_sizes[1] / 2;     // 800000
    const int M0 = in_sizes[9];         // 512
    const int M1 = in_sizes[11];        // 256
    const int Npad = ((N + 127) / 128) * 128;   // 50048
    const int nblk1024 = (N + 1023) / 1024;

    const int* src = ei;
    const int* dst = ei + E;

    char* ws = (char*)d_ws;
    size_t off = 0;
    auto alloc = [&](size_t bytes) {
        void* p = ws + off;
        off += (bytes + 255) & ~(size_t)255;
        return p;
    };
    int* degi   = (int*)alloc((size_t)N * 4);
    int* tmp    = (int*)alloc((size_t)N * 4);
    int* bsums  = (int*)alloc(4096);
    int* rowptr = (int*)alloc((size_t)(N + 1) * 4);
    int* cursor = (int*)alloc((size_t)N * 4);
    int* colbuf = (int*)alloc((size_t)E * 4);
    float* dinv = (float*)alloc((size_t)N * 4);
    unsigned short* WgT_hi[3];
    unsigned short* WgT_lo[3];
    for (int l = 0; l < 3; ++l) {
        WgT_hi[l] = (unsigned short*)alloc((size_t)HID * HID * 2);
        WgT_lo[l] = (unsigned short*)alloc((size_t)HID * HID * 2);
    }
    unsigned short* Wm0T_hi = (unsigned short*)alloc((size_t)M0 * HID * 2);
    unsigned short* Wm0T_lo = (unsigned short*)alloc((size_t)M0 * HID * 2);
    unsigned short* Wm1T_hi = (unsigned short*)alloc((size_t)M1 * M0 * 2);
    unsigned short* Wm1T_lo = (unsigned short*)alloc((size_t)M1 * M0 * 2);
    unsigned short* Chi = (unsigned short*)alloc((size_t)Npad * HID * 2);
    unsigned short* Clo = (unsigned short*)alloc((size_t)Npad * HID * 2);
    char* R = (char*)alloc((size_t)Npad * M0 * 2 * 2);  // overlay region
    unsigned short* Xhi = (unsigned short*)R;
    unsigned short* Xlo = (unsigned short*)(R + (size_t)Npad * HID * 2);
    float* A = (float*)(R + (size_t)Npad * HID * 4);           // hs fp32 [N][HID]
    unsigned short* Mhi = (unsigned short*)R;
    unsigned short* Mlo = (unsigned short*)(R + (size_t)Npad * M0 * 2);

    // ---- CSR build ----
    hipMemsetAsync(degi, 0, (size_t)N * 4, stream);
    deg_int_kernel<<<(E + 255) / 256, 256, 0, stream>>>(dst, degi, E);
    scan1_kernel<<<nblk1024, 1024, 0, stream>>>(degi, tmp, bsums, N);
    scan2_kernel<<<1, 1024, 0, stream>>>(bsums, nblk1024);
    scan3_kernel<<<(N + 255) / 256, 256, 0, stream>>>(tmp, degi, bsums, rowptr, cursor, dinv, N, E);
    fill_kernel<<<(E + 255) / 256, 256, 0, stream>>>(src, dst, cursor, colbuf, E);

    // ---- conversions ----
    xsplit_kernel<<<(N * HID / 4 + 255) / 256, 256, 0, stream>>>(x, Xhi, Xlo, N * HID / 4);
    const float* WgArr[3] = {Wg0, Wg1, Wg2};
    for (int l = 0; l < 3; ++l)
        wsplit_kernel<<<(HID * HID + 255) / 256, 256, 0, stream>>>(WgArr[l], WgT_hi[l], WgT_lo[l], HID, HID);
    wsplit_kernel<<<(HID * M0 + 255) / 256, 256, 0, stream>>>(Wm0, Wm0T_hi, Wm0T_lo, HID, M0);
    wsplit_kernel<<<(M0 * M1 + 255) / 256, 256, 0, stream>>>(Wm1, Wm1T_hi, Wm1T_lo, M0, M1);

    // ---- 3 GCN layers ----
    const float* bg[3] = {bg0, bg1, bg2};
    const unsigned short* curHi = Xhi;
    const unsigned short* curLo = Xlo;
    long long gatherThreads = (long long)N * 32;
    for (int l = 0; l < 3; ++l) {
        gemm_mfma<true, false, false, false><<<dim3(1, Npad / 128), 256, 0, stream>>>(
            curHi, curLo, WgT_hi[l], WgT_lo[l], nullptr, dinv, A, nullptr, nullptr, N, HID, HID);
        gather_kernel<<<(int)((gatherThreads + 255) / 256), 256, 0, stream>>>(
            A, rowptr, colbuf, dinv, bg[l], Chi, Clo, N);
        curHi = Chi;
        curLo = Clo;
    }

    // ---- MLP head ----
    gemm_mfma<false, true, true, true><<<dim3(M0 / 128, Npad / 128), 256, 0, stream>>>(
        Chi, Clo, Wm0T_hi, Wm0T_lo, bm0, nullptr, nullptr, Mhi, Mlo, N, HID, M0);
    gemm_mfma<false, true, true, false><<<dim3(M1 / 128, Npad / 128), 256, 0, stream>>>(
        Mhi, Mlo, Wm1T_hi, Wm1T_lo, bm1, nullptr, out, nullptr, nullptr, N, M0, M1);
}

// Round 5
// 542.134 us; speedup vs baseline: 8.6469x; 1.0275x over previous
//
#include <hip/hip_runtime.h>

#define HID 128

using short8  = __attribute__((ext_vector_type(8))) short;
using float4v = __attribute__((ext_vector_type(4))) float;

// ---- fp32 -> bf16 (RNE) helpers ----
__device__ __forceinline__ unsigned short f2bf(float f) {
    unsigned u = __float_as_uint(f);
    u = u + 0x7fff + ((u >> 16) & 1);
    return (unsigned short)(u >> 16);
}
__device__ __forceinline__ float bf2f(unsigned short h) {
    return __uint_as_float(((unsigned)h) << 16);
}
__device__ __forceinline__ void split2(float x, unsigned short& hi, unsigned short& lo) {
    hi = f2bf(x);
    lo = f2bf(x - bf2f(hi));
}

// ---- async global->LDS, 16 B per lane (wave-uniform base + lane*16) ----
typedef const __attribute__((address_space(1))) unsigned int* gas_ptr;
typedef __attribute__((address_space(3))) unsigned int* las_ptr;
__device__ __forceinline__ void gld16(const unsigned short* g, unsigned short* l) {
    __builtin_amdgcn_global_load_lds((gas_ptr)g, (las_ptr)l, 16, 0, 0);
}

// ---------------- CSR build ----------------

__global__ void deg_int_kernel(const int* __restrict__ dst, int* __restrict__ degi, int E) {
    int i = blockIdx.x * blockDim.x + threadIdx.x;
    if (i < E) atomicAdd(&degi[dst[i]], 1);
}

__global__ __launch_bounds__(1024) void scan1_kernel(
    const int* __restrict__ in, int* __restrict__ incl, int* __restrict__ bsums, int N) {
    __shared__ int sm[1024];
    int i = blockIdx.x * 1024 + threadIdx.x;
    int v = (i < N) ? in[i] : 0;
    sm[threadIdx.x] = v;
    __syncthreads();
    for (int off = 1; off < 1024; off <<= 1) {
        int t = (threadIdx.x >= (unsigned)off) ? sm[threadIdx.x - off] : 0;
        __syncthreads();
        sm[threadIdx.x] += t;
        __syncthreads();
    }
    if (i < N) incl[i] = sm[threadIdx.x];
    if (threadIdx.x == 1023) bsums[blockIdx.x] = sm[1023];
}

__global__ __launch_bounds__(1024) void scan2_kernel(int* __restrict__ bsums, int nblk) {
    __shared__ int sm[1024];
    int t = threadIdx.x;
    int v = (t < nblk) ? bsums[t] : 0;
    sm[t] = v;
    __syncthreads();
    for (int off = 1; off < 1024; off <<= 1) {
        int u = (t >= (unsigned)off) ? sm[t - off] : 0;
        __syncthreads();
        sm[t] += u;
        __syncthreads();
    }
    if (t < nblk) bsums[t] = sm[t] - v;  // exclusive
}

__global__ void scan3_kernel(const int* __restrict__ incl, const int* __restrict__ degi,
                             const int* __restrict__ bsums, int* __restrict__ rowptr,
                             int* __restrict__ cursor, float* __restrict__ dinv, int N, int E) {
    int i = blockIdx.x * blockDim.x + threadIdx.x;
    if (i < N) {
        int r = bsums[i >> 10] + incl[i] - degi[i];
        rowptr[i] = r;
        cursor[i] = r;
        dinv[i] = rsqrtf((float)degi[i] + 1.0f);
    }
    if (i == 0) rowptr[N] = E;
}

__global__ void fill_kernel(const int* __restrict__ src, const int* __restrict__ dst,
                            int* __restrict__ cursor, int* __restrict__ col, int E) {
    int e = blockIdx.x * blockDim.x + threadIdx.x;
    if (e < E) {
        int d = dst[e];
        int pos = atomicAdd(&cursor[d], 1);
        col[pos] = src[e];
    }
}

// ---------------- input / weight conversion ----------------

__global__ void xsplit_kernel(const float* __restrict__ x, unsigned short* __restrict__ Xhi,
                              unsigned short* __restrict__ Xlo, int total4) {
    int i = blockIdx.x * blockDim.x + threadIdx.x;
    if (i >= total4) return;
    const float4 v = *(const float4*)(x + (size_t)i * 4);
    ushort4 h, l;
    split2(v.x, h.x, l.x);
    split2(v.y, h.y, l.y);
    split2(v.z, h.z, l.z);
    split2(v.w, h.w, l.w);
    *(ushort4*)(Xhi + (size_t)i * 4) = h;
    *(ushort4*)(Xlo + (size_t)i * 4) = l;
}

// all 5 weight matrices transposed+split in one dispatch
struct WSegs {
    const float* W[5];
    unsigned short* hi[5];
    unsigned short* lo[5];
    int K[5], M[5], start[5];  // start element index of each segment
};

__global__ void wsplit_all_kernel(WSegs S, int total) {
    int idx = blockIdx.x * blockDim.x + threadIdx.x;
    if (idx >= total) return;
    int s = 0;
#pragma unroll
    for (int t = 1; t < 5; ++t)
        if (idx >= S.start[t]) s = t;
    int local = idx - S.start[s];
    int M = S.M[s], K = S.K[s];
    int k = local / M;
    int m = local - k * M;
    unsigned short hi, lo;
    split2(S.W[s][local], hi, lo);
    S.hi[s][(size_t)m * K + k] = hi;
    S.lo[s][(size_t)m * K + k] = lo;
}

// ---------------- fused gather-reduce + finalize -> split planes ----------------
__global__ __launch_bounds__(256) void gather_kernel(
    const float* __restrict__ hs, const int* __restrict__ rowptr,
    const int* __restrict__ col, const float* __restrict__ dinv,
    const float* __restrict__ bias, unsigned short* __restrict__ Chi,
    unsigned short* __restrict__ Clo, int N) {
    long long idx = (long long)blockIdx.x * blockDim.x + threadIdx.x;
    int i = (int)(idx >> 5);
    if (i >= N) return;
    int c = ((int)idx & 31) * 4;

    int beg = rowptr[i];
    int end = rowptr[i + 1];

    float4 acc = *(const float4*)(hs + (size_t)i * HID + c);  // self-loop

    int j = beg;
    for (; j + 4 <= end; j += 4) {
        int s0 = col[j], s1 = col[j + 1], s2 = col[j + 2], s3 = col[j + 3];
        const float4 v0 = *(const float4*)(hs + (size_t)s0 * HID + c);
        const float4 v1 = *(const float4*)(hs + (size_t)s1 * HID + c);
        const float4 v2 = *(const float4*)(hs + (size_t)s2 * HID + c);
        const float4 v3 = *(const float4*)(hs + (size_t)s3 * HID + c);
        acc.x += (v0.x + v1.x) + (v2.x + v3.x);
        acc.y += (v0.y + v1.y) + (v2.y + v3.y);
        acc.z += (v0.z + v1.z) + (v2.z + v3.z);
        acc.w += (v0.w + v1.w) + (v2.w + v3.w);
    }
    for (; j < end; ++j) {
        int s = col[j];
        const float4 v = *(const float4*)(hs + (size_t)s * HID + c);
        acc.x += v.x; acc.y += v.y; acc.z += v.z; acc.w += v.w;
    }

    float di = dinv[i];
    float4 b = *(const float4*)(bias + c);
    float rx = fmaxf(acc.x * di + b.x, 0.0f);
    float ry = fmaxf(acc.y * di + b.y, 0.0f);
    float rz = fmaxf(acc.z * di + b.z, 0.0f);
    float rw = fmaxf(acc.w * di + b.w, 0.0f);
    ushort4 h, l;
    split2(rx, h.x, l.x);
    split2(ry, h.y, l.y);
    split2(rz, h.z, l.z);
    split2(rw, h.w, l.w);
    *(ushort4*)(Chi + (size_t)i * HID + c) = h;
    *(ushort4*)(Clo + (size_t)i * HID + c) = l;
}

// ---------------- split-bf16 MFMA GEMM with async LDS staging + XOR swizzle ----------------
// C[N x M] = epilogue(A[N x K] @ W[K x M]); A = bf16 hi/lo planes [Npad][K],
// W = transposed bf16 hi/lo planes [M][K].
// BM=128: 4 waves (2x2), wave tile 64x64 (TM=4,TN=4).
// BM=64 : 4 waves (1x4), wave tile 64x32 (TM=4,TN=2). BN always 128.
// LDS layout per plane: 16B granule for (row r, k-quad q) at slot r*4 + (q^(r&3)).
// a*b ~= ah*bh + ah*bl + al*bh  (3 MFMA / tile / 32-k chunk).
template <int BM, bool SCALE, bool BIAS, bool RELU, bool SPLIT>
__global__ __launch_bounds__(256, (BM == 64) ? 4 : 3) void gemm_mfma(
    const unsigned short* __restrict__ Ahi, const unsigned short* __restrict__ Alo,
    const unsigned short* __restrict__ Bhi, const unsigned short* __restrict__ Blo,
    const float* __restrict__ bias, const float* __restrict__ rowscale,
    float* __restrict__ outF, unsigned short* __restrict__ outHi,
    unsigned short* __restrict__ outLo, int Nout, int K, int M) {
    constexpr int TN = (BM == 128) ? 4 : 2;
    __shared__ unsigned short lds[(2 * BM + 2 * 128) * 32];
    unsigned short* Ah = lds;                       // BM*32
    unsigned short* Al = lds + BM * 32;             // BM*32
    unsigned short* Bh = lds + 2 * BM * 32;         // 128*32
    unsigned short* Bl = lds + 2 * BM * 32 + 128 * 32;

    const int tid = threadIdx.x;
    const int bm = blockIdx.y * BM;
    const int bn = blockIdx.x * 128;
    const int wave = tid >> 6, lane = tid & 63;
    const int quad = lane >> 4, c16 = lane & 15;
    const int wm = (BM == 128) ? (wave >> 1) * 64 : 0;
    const int wn = (BM == 128) ? (wave & 1) * 64 : wave * 32;

    float4v acc[4][TN];
#pragma unroll
    for (int a = 0; a < 4; ++a)
#pragma unroll
        for (int b = 0; b < TN; ++b)
#pragma unroll
            for (int r = 0; r < 4; ++r) acc[a][b][r] = 0.0f;

    // staging: thread tid owns LDS slot tid (and tid+256 for 128-row tiles).
    // slot s holds global (row = s>>2, kq = (s&3) ^ (row&3)).
    const int r0 = tid >> 2;                        // 0..63
    const int q0 = (tid & 3) ^ (r0 & 3);            // permuted k-quad (same for row r0+64)
    const int kq0 = q0 * 8;

    const unsigned short* gAh0 = Ahi + (size_t)(bm + r0) * K + kq0;
    const unsigned short* gAl0 = Alo + (size_t)(bm + r0) * K + kq0;
    const unsigned short* gBh0 = Bhi + (size_t)(bn + r0) * K + kq0;
    const unsigned short* gBh1 = Bhi + (size_t)(bn + r0 + 64) * K + kq0;
    const unsigned short* gBl0 = Blo + (size_t)(bn + r0) * K + kq0;
    const unsigned short* gBl1 = Blo + (size_t)(bn + r0 + 64) * K + kq0;
    const unsigned short* gAh1 = nullptr;
    const unsigned short* gAl1 = nullptr;
    if constexpr (BM == 128) {
        gAh1 = Ahi + (size_t)(bm + r0 + 64) * K + kq0;
        gAl1 = Alo + (size_t)(bm + r0 + 64) * K + kq0;
    }

    unsigned short* lAh0 = Ah + (size_t)tid * 8;
    unsigned short* lAl0 = Al + (size_t)tid * 8;
    unsigned short* lBh0 = Bh + (size_t)tid * 8;
    unsigned short* lBh1 = Bh + (size_t)(tid + 256) * 8;
    unsigned short* lBl0 = Bl + (size_t)tid * 8;
    unsigned short* lBl1 = Bl + (size_t)(tid + 256) * 8;
    unsigned short* lAh1 = Ah + (size_t)(tid + 256) * 8;
    unsigned short* lAl1 = Al + (size_t)(tid + 256) * 8;

    // fragment-read swizzle: row am has am&3 == c16&3 for all tiles
    const int sw = (quad ^ (c16 & 3)) * 8;

    for (int k0 = 0; k0 < K; k0 += 32) {
        if (k0 != 0) __syncthreads();  // all waves done reading previous chunk
        gld16(gAh0 + k0, lAh0);
        gld16(gAl0 + k0, lAl0);
        if constexpr (BM == 128) {
            gld16(gAh1 + k0, lAh1);
            gld16(gAl1 + k0, lAl1);
        }
        gld16(gBh0 + k0, lBh0);
        gld16(gBh1 + k0, lBh1);
        gld16(gBl0 + k0, lBl0);
        gld16(gBl1 + k0, lBl1);
        __syncthreads();               // drains vmcnt (DMA done) + barrier

        short8 afh[4], afl[4], bfh[TN], bfl[TN];
#pragma unroll
        for (int t = 0; t < 4; ++t) {
            int am = wm + t * 16 + c16;
            afh[t] = *(const short8*)&Ah[am * 32 + sw];
            afl[t] = *(const short8*)&Al[am * 32 + sw];
        }
#pragma unroll
        for (int t = 0; t < TN; ++t) {
            int bn_ = wn + t * 16 + c16;
            bfh[t] = *(const short8*)&Bh[bn_ * 32 + sw];
            bfl[t] = *(const short8*)&Bl[bn_ * 32 + sw];
        }
#pragma unroll
        for (int tm = 0; tm < 4; ++tm)
#pragma unroll
            for (int tn = 0; tn < TN; ++tn) {
                acc[tm][tn] = __builtin_amdgcn_mfma_f32_16x16x32_bf16(afh[tm], bfh[tn], acc[tm][tn], 0, 0, 0);
                acc[tm][tn] = __builtin_amdgcn_mfma_f32_16x16x32_bf16(afh[tm], bfl[tn], acc[tm][tn], 0, 0, 0);
                acc[tm][tn] = __builtin_amdgcn_mfma_f32_16x16x32_bf16(afl[tm], bfh[tn], acc[tm][tn], 0, 0, 0);
            }
    }

    // epilogue: C/D layout col=lane&15, row=quad*4+reg
#pragma unroll
    for (int tm = 0; tm < 4; ++tm) {
#pragma unroll
        for (int tn = 0; tn < TN; ++tn) {
            int colg = bn + wn + tn * 16 + c16;
            float bv = BIAS ? bias[colg] : 0.0f;
#pragma unroll
            for (int r = 0; r < 4; ++r) {
                int row = bm + wm + tm * 16 + quad * 4 + r;
                if (row >= Nout) continue;
                float v = acc[tm][tn][r];
                if (SCALE) v *= rowscale[row];
                if (BIAS) v += bv;
                if (RELU) v = fmaxf(v, 0.0f);
                if (SPLIT) {
                    unsigned short hi, lo;
                    split2(v, hi, lo);
                    outHi[(size_t)row * M + colg] = hi;
                    outLo[(size_t)row * M + colg] = lo;
                } else {
                    outF[(size_t)row * M + colg] = v;
                }
            }
        }
    }
}

// ---------------- host launch ----------------

extern "C" void kernel_launch(void* const* d_in, const int* in_sizes, int n_in,
                              void* d_out, int out_size, void* d_ws, size_t ws_size,
                              hipStream_t stream) {
    const float* x   = (const float*)d_in[0];
    const int*   ei  = (const int*)d_in[1];
    const float* Wg0 = (const float*)d_in[2];
    const float* bg0 = (const float*)d_in[3];
    const float* Wg1 = (const float*)d_in[4];
    const float* bg1 = (const float*)d_in[5];
    const float* Wg2 = (const float*)d_in[6];
    const float* bg2 = (const float*)d_in[7];
    const float* Wm0 = (const float*)d_in[8];
    const float* bm0 = (const float*)d_in[9];
    const float* Wm1 = (const float*)d_in[10];
    const float* bm1 = (const float*)d_in[11];
    float* out = (float*)d_out;

    const int N  = in_sizes[0] / HID;   // 50000
    const int E  = in_sizes[1] / 2;     // 800000
    const int M0 = in_sizes[9];         // 512
    const int M1 = in_sizes[11];        // 256
    const int Npad = ((N + 127) / 128) * 128;   // 50048 (multiple of 64 and 128)
    const int nblk1024 = (N + 1023) / 1024;

    const int* src = ei;
    const int* dst = ei + E;

    char* ws = (char*)d_ws;
    size_t off = 0;
    auto alloc = [&](size_t bytes) {
        void* p = ws + off;
        off += (bytes + 255) & ~(size_t)255;
        return p;
    };
    int* degi   = (int*)alloc((size_t)N * 4);
    int* tmp    = (int*)alloc((size_t)N * 4);
    int* bsums  = (int*)alloc(4096);
    int* rowptr = (int*)alloc((size_t)(N + 1) * 4);
    int* cursor = (int*)alloc((size_t)N * 4);
    int* colbuf = (int*)alloc((size_t)E * 4);
    float* dinv = (float*)alloc((size_t)N * 4);
    unsigned short* WgT_hi[3];
    unsigned short* WgT_lo[3];
    for (int l = 0; l < 3; ++l) {
        WgT_hi[l] = (unsigned short*)alloc((size_t)HID * HID * 2);
        WgT_lo[l] = (unsigned short*)alloc((size_t)HID * HID * 2);
    }
    unsigned short* Wm0T_hi = (unsigned short*)alloc((size_t)M0 * HID * 2);
    unsigned short* Wm0T_lo = (unsigned short*)alloc((size_t)M0 * HID * 2);
    unsigned short* Wm1T_hi = (unsigned short*)alloc((size_t)M1 * M0 * 2);
    unsigned short* Wm1T_lo = (unsigned short*)alloc((size_t)M1 * M0 * 2);
    unsigned short* Chi = (unsigned short*)alloc((size_t)Npad * HID * 2);
    unsigned short* Clo = (unsigned short*)alloc((size_t)Npad * HID * 2);
    char* R = (char*)alloc((size_t)Npad * M0 * 2 * 2);  // overlay region
    unsigned short* Xhi = (unsigned short*)R;
    unsigned short* Xlo = (unsigned short*)(R + (size_t)Npad * HID * 2);
    float* A = (float*)(R + (size_t)Npad * HID * 4);    // hs fp32 [N][HID]
    unsigned short* Mhi = (unsigned short*)R;
    unsigned short* Mlo = (unsigned short*)(R + (size_t)Npad * M0 * 2);

    // ---- CSR build ----
    hipMemsetAsync(degi, 0, (size_t)N * 4, stream);
    deg_int_kernel<<<(E + 255) / 256, 256, 0, stream>>>(dst, degi, E);
    scan1_kernel<<<nblk1024, 1024, 0, stream>>>(degi, tmp, bsums, N);
    scan2_kernel<<<1, 1024, 0, stream>>>(bsums, nblk1024);
    scan3_kernel<<<(N + 255) / 256, 256, 0, stream>>>(tmp, degi, bsums, rowptr, cursor, dinv, N, E);
    fill_kernel<<<(E + 255) / 256, 256, 0, stream>>>(src, dst, cursor, colbuf, E);

    // ---- conversions ----
    xsplit_kernel<<<(N * HID / 4 + 255) / 256, 256, 0, stream>>>(x, Xhi, Xlo, N * HID / 4);
    {
        WSegs S;
        const float* Ws[5]      = {Wg0, Wg1, Wg2, Wm0, Wm1};
        unsigned short* His[5]  = {WgT_hi[0], WgT_hi[1], WgT_hi[2], Wm0T_hi, Wm1T_hi};
        unsigned short* Los[5]  = {WgT_lo[0], WgT_lo[1], WgT_lo[2], Wm0T_lo, Wm1T_lo};
        int Ks[5] = {HID, HID, HID, HID, M0};
        int Ms[5] = {HID, HID, HID, M0, M1};
        int start = 0;
        for (int s = 0; s < 5; ++s) {
            S.W[s] = Ws[s]; S.hi[s] = His[s]; S.lo[s] = Los[s];
            S.K[s] = Ks[s]; S.M[s] = Ms[s]; S.start[s] = start;
            start += Ks[s] * Ms[s];
        }
        wsplit_all_kernel<<<(start + 255) / 256, 256, 0, stream>>>(S, start);
    }

    // ---- 3 GCN layers ----
    const float* bg[3] = {bg0, bg1, bg2};
    const unsigned short* curHi = Xhi;
    const unsigned short* curLo = Xlo;
    long long gatherThreads = (long long)N * 32;
    for (int l = 0; l < 3; ++l) {
        gemm_mfma<64, true, false, false, false><<<dim3(1, Npad / 64), 256, 0, stream>>>(
            curHi, curLo, WgT_hi[l], WgT_lo[l], nullptr, dinv, A, nullptr, nullptr, N, HID, HID);
        gather_kernel<<<(int)((gatherThreads + 255) / 256), 256, 0, stream>>>(
            A, rowptr, colbuf, dinv, bg[l], Chi, Clo, N);
        curHi = Chi;
        curLo = Clo;
    }

    // ---- MLP head ----
    gemm_mfma<128, false, true, true, true><<<dim3(M0 / 128, Npad / 128), 256, 0, stream>>>(
        Chi, Clo, Wm0T_hi, Wm0T_lo, bm0, nullptr, nullptr, Mhi, Mlo, N, HID, M0);
    gemm_mfma<128, false, true, true, false><<<dim3(M1 / 128, Npad / 128), 256, 0, stream>>>(
        Mhi, Mlo, Wm1T_hi, Wm1T_lo, bm1, nullptr, out, nullptr, nullptr, N, M0, M1);
}